// Round 11
// baseline (1950.741 us; speedup 1.0000x reference)
//
#include <hip/hip_runtime.h>
#include <math.h>

#define TT 256
#define H1 100
#define H2 50
#define NT 512
#define NBLK 512   // 4096 rows / 8 per block; 2 blocks per CU
#define ROWS 8

typedef __attribute__((ext_vector_type(8))) short bf16x8;
typedef __attribute__((ext_vector_type(4))) float f32x4;

__device__ __forceinline__ float sigf(float x) {
    return __builtin_amdgcn_rcpf(1.0f + __expf(-x));
}
__device__ __forceinline__ float tanhfast(float x) {
    return 1.0f - 2.0f * __builtin_amdgcn_rcpf(1.0f + __expf(2.0f * x));
}
__device__ __forceinline__ short f2bf(float f) {
    union { float f; unsigned u; } v; v.f = f;
    unsigned r = v.u + 0x7FFFu + ((v.u >> 16) & 1u);  // RNE
    return (short)(r >> 16);
}

// fragment-linear byte offset: element (K,R) of a [chunk][64 lane][8 bf16] buf
__device__ __forceinline__ int off_frag(int K, int R) {
    return (K >> 5) * 1024 + ((K >> 3) & 3) * 256 + R * 16 + (K & 7) * 2;
}

#define MFMA(w, b, c) __builtin_amdgcn_mfma_f32_16x16x32_bf16(w, b, c, 0, 0, 0)

__device__ __forceinline__ float cellup(const f32x4& a, float& cst) {
    const float is = sigf(a[0]), fs = sigf(a[1]);
    const float gt = tanhfast(a[2]), os = sigf(a[3]);
    const float c = fs * cst + is * gt;
    cst = c;
    return os * tanhfast(c);
}

// ---- weight fragment loaders (round-4/7 proven; run once) ----
__device__ __forceinline__ void load_w1(bf16x8* dst, int T, int r, int q,
                                        const float* W_hh1, const float* W_ih1) {
    const int jp = T * 16 + r, g = jp & 3, uu = jp >> 2;   // uu < 100
#pragma unroll
    for (int c = 0; c < 4; ++c) {
        bf16x8 w;
#pragma unroll
        for (int i = 0; i < 8; ++i) {
            const int k = c * 32 + q * 8 + i;
            float f = 0.f;
            if (k < H1) f = W_hh1[(g * H1 + uu) * H1 + k];
            else if (k < H1 + 8) f = W_ih1[(g * H1 + uu) * 8 + (k - H1)];
            w[i] = f2bf(f);
        }
        dst[c] = w;
    }
}
__device__ __forceinline__ void load_w2(bf16x8* dst, int t2, int r, int q,
                                        const float* W_ih2, const float* W_hh2) {
    const int jp = t2 * 16 + r, g = jp & 3, uu = jp >> 2;
    const bool ok = uu < H2;
#pragma unroll
    for (int c = 0; c < 6; ++c) {
        bf16x8 w;
#pragma unroll
        for (int i = 0; i < 8; ++i) {
            float f = 0.f;
            if (ok) {
                if (c < 4) {
                    const int k = c * 32 + q * 8 + i;
                    if (k < H1) f = W_ih2[(g * H2 + uu) * H1 + k];
                } else {
                    const int k2 = (c - 4) * 32 + q * 8 + i;
                    if (k2 < H2) f = W_hh2[(g * H2 + uu) * H2 + k2];
                }
            }
            w[i] = f2bf(f);
        }
        dst[c] = w;
    }
}

__global__ __launch_bounds__(NT, 4) void lstm_ws6(
    const float* __restrict__ x,
    const float* __restrict__ W_ih1, const float* __restrict__ W_hh1,
    const float* __restrict__ b_ih1, const float* __restrict__ b_hh1,
    const float* __restrict__ W_ih2, const float* __restrict__ W_hh2,
    const float* __restrict__ b_ih2, const float* __restrict__ b_hh2,
    const float* __restrict__ Wd, const float* __restrict__ bd,
    float* __restrict__ out)
{
    __shared__ __align__(16) short xb[TT * ROWS * 8];   // 32 KB bf16 x
    __shared__ __align__(16) short A1h[2 * 4 * 64 * 8]; // 8 KB
    __shared__ __align__(16) short h2b[2 * 2 * 64 * 8]; // 4 KB
    __shared__ float hscr[ROWS * 52];                   // 1.7 KB

    const int tid = threadIdx.x;
    const int lane = tid & 63;
    const int wv = tid >> 6;       // 8 waves
    const int r = lane & 15;       // fragment col; only r<8 are real rows
    const int q = lane >> 4;
    const int row0 = blockIdx.x * ROWS;
    const bool rok = (r < ROWS);

    char* const a1b = (char*)A1h;
    char* const h2bb = (char*)h2b;

    // ---- fill xb: [t][r][8] bf16, t-stride 128B ----
    {
        const float* xg = x + (size_t)row0 * (TT * 8);
#pragma unroll
        for (int it = 0; it < 8; ++it) {
            const int f = (it * NT + tid) * 4;       // 0..16383
            const float4 v = *(const float4*)(xg + f);
            const int rr = f >> 11, rem = f & 2047, t = rem >> 3, k = rem & 7;
            uint2 pk;
            pk.x = (unsigned short)f2bf(v.x) | ((unsigned)(unsigned short)f2bf(v.y) << 16);
            pk.y = (unsigned short)f2bf(v.z) | ((unsigned)(unsigned short)f2bf(v.w) << 16);
            *(uint2*)((char*)xb + t * 128 + rr * 16 + k * 2) = pk;
        }
    }
    for (int i = tid; i < 2 * 4 * 64 * 8; i += NT) A1h[i] = 0;
    for (int i = tid; i < 2 * 2 * 64 * 8; i += NT) h2b[i] = 0;
    if (tid < ROWS * 52) hscr[tid] = 0.f;

    // ---- slot composition (round-7 map) ----
    // slots 0..2: L1 tile wv + sl*8 (0..23)
    // slot 3: wv==0 -> L1 tile 24; wv 1..5 -> L2 tile wv+7; wv 6,7 -> dead
    // slot 4: L2 tile wv (0..7)
    bf16x8 wfA0[4], wfA1[4], wfA2[4], wfB[6], wfC[6];
    f32x4 bv0, bv1, bv2, bv3 = {0.f, 0.f, 0.f, 0.f}, bv4;
    int wof0, wof1, wof2, wof3 = 0, wof4;
    int hso3 = 0, hso4;
    bool ok3 = false;

    load_w1(wfA0, wv + 0, r, q, W_hh1, W_ih1);
    load_w1(wfA1, wv + 8, r, q, W_hh1, W_ih1);
    load_w1(wfA2, wv + 16, r, q, W_hh1, W_ih1);
    {
        const int u0 = (wv + 0) * 4 + q, u1 = (wv + 8) * 4 + q, u2_ = (wv + 16) * 4 + q;
#pragma unroll
        for (int g = 0; g < 4; ++g) {
            bv0[g] = b_ih1[g * H1 + u0] + b_hh1[g * H1 + u0];
            bv1[g] = b_ih1[g * H1 + u1] + b_hh1[g * H1 + u1];
            bv2[g] = b_ih1[g * H1 + u2_] + b_hh1[g * H1 + u2_];
        }
        wof0 = off_frag(u0, r); wof1 = off_frag(u1, r); wof2 = off_frag(u2_, r);
    }
    if (wv == 0) {            // slot3 = L1 tile 24
        load_w1(wfB, 24, r, q, W_hh1, W_ih1);
        wfB[4] = (bf16x8){0,0,0,0,0,0,0,0};
        wfB[5] = (bf16x8){0,0,0,0,0,0,0,0};
        const int u = 96 + q;
#pragma unroll
        for (int g = 0; g < 4; ++g) bv3[g] = b_ih1[g * H1 + u] + b_hh1[g * H1 + u];
        wof3 = off_frag(u, r);
        ok3 = true;
    } else if (wv <= 5) {     // slot3 = L2 tile wv+7
        load_w2(wfB, wv + 7, r, q, W_ih2, W_hh2);
        const int u2 = (wv + 7) * 4 + q;
        ok3 = (u2 < H2);
#pragma unroll
        for (int g = 0; g < 4; ++g)
            bv3[g] = ok3 ? (b_ih2[g * H2 + u2] + b_hh2[g * H2 + u2]) : 0.f;
        wof3 = off_frag(u2 & 63, r);
        hso3 = (r & 7) * 52 + u2;
    } else {                  // wv 6,7: dead slot3 (uniform shape, no store)
#pragma unroll
        for (int c = 0; c < 6; ++c) wfB[c] = (bf16x8){0,0,0,0,0,0,0,0};
    }
    {                          // slot4 = L2 tile wv (u2 <= 31, always valid)
        load_w2(wfC, wv, r, q, W_ih2, W_hh2);
        const int u2 = wv * 4 + q;
#pragma unroll
        for (int g = 0; g < 4; ++g) bv4[g] = b_ih2[g * H2 + u2] + b_hh2[g * H2 + u2];
        wof4 = off_frag(u2, r);
        hso4 = (r & 7) * 52 + u2;
    }

    float cst0 = 0.f, cst1 = 0.f, cst2 = 0.f, cst3 = 0.f, cst4 = 0.f;

    const bool wstage = ((tid >> 4) == 28) && ((tid & 15) < ROWS); // wave 7
    const int st = tid & 7;

    __syncthreads();
    // stage x(0) into buf0 chunk 3 (rows 0..7; rows 8..15 stay zero)
    if (tid < ROWS) {
        bf16x8 v = *(const bf16x8*)((const char*)xb + tid * 16);
        uint2 lo = ((const uint2*)&v)[0], hi = ((const uint2*)&v)[1];
        char* dst = a1b + 3 * 1024 + tid * 16;
        *(uint2*)(dst + 8) = lo;
        *(uint2*)(dst + 256) = hi;
    }
    __syncthreads();

    // ==== main loop: superstep s computes h1(s) and (s>0) h2(s-1) ====
    for (int s = 0; s < TT; ++s) {
        const int cur = s & 1;
        char* a1r = a1b + (cur << 12);
        char* h2r = h2bb + (cur << 11);
        char* a1w = a1b + ((cur ^ 1) << 12);
        char* h2w = h2bb + ((cur ^ 1) << 11);

        const bf16x8 bA0 = *(const bf16x8*)(a1r + 0 * 1024 + lane * 16);
        const bf16x8 bA1 = *(const bf16x8*)(a1r + 1 * 1024 + lane * 16);
        const bf16x8 bA2 = *(const bf16x8*)(a1r + 2 * 1024 + lane * 16);
        const bf16x8 bA3 = *(const bf16x8*)(a1r + 3 * 1024 + lane * 16);
        const bf16x8 bH0 = *(const bf16x8*)(h2r + 0 * 1024 + lane * 16);
        const bf16x8 bH1 = *(const bf16x8*)(h2r + 1 * 1024 + lane * 16);

        if (wstage && s + 1 < TT) {
            bf16x8 v = *(const bf16x8*)((const char*)xb + (s + 1) * 128 + st * 16);
            uint2 lo = ((const uint2*)&v)[0], hi = ((const uint2*)&v)[1];
            char* dst = a1w + 3 * 1024 + st * 16;
            *(uint2*)(dst + 8) = lo;
            *(uint2*)(dst + 256) = hi;
        }

        // ---- 24 MFMAs, 5-way interleaved; first op consumes bias as C ----
        f32x4 a0 = MFMA(wfA0[0], bA0, bv0);
        f32x4 a1 = MFMA(wfA1[0], bA0, bv1);
        f32x4 a2 = MFMA(wfA2[0], bA0, bv2);
        f32x4 a3 = MFMA(wfB[0], bA0, bv3);
        f32x4 a4 = MFMA(wfC[0], bA0, bv4);
        a0 = MFMA(wfA0[1], bA1, a0);
        a1 = MFMA(wfA1[1], bA1, a1);
        a2 = MFMA(wfA2[1], bA1, a2);
        a3 = MFMA(wfB[1], bA1, a3);
        a4 = MFMA(wfC[1], bA1, a4);
        a0 = MFMA(wfA0[2], bA2, a0);
        a1 = MFMA(wfA1[2], bA2, a1);
        a2 = MFMA(wfA2[2], bA2, a2);
        a3 = MFMA(wfB[2], bA2, a3);
        a4 = MFMA(wfC[2], bA2, a4);
        a0 = MFMA(wfA0[3], bA3, a0);
        a1 = MFMA(wfA1[3], bA3, a1);
        a2 = MFMA(wfA2[3], bA3, a2);
        a3 = MFMA(wfB[3], bA3, a3);
        a4 = MFMA(wfC[3], bA3, a4);
        a3 = MFMA(wfB[4], bH0, a3);
        a4 = MFMA(wfC[4], bH0, a4);
        a3 = MFMA(wfB[5], bH1, a3);
        a4 = MFMA(wfC[5], bH1, a4);

        // ---- nonlinearities + state writes (store-guarded to r<8) ----
        const float h0 = cellup(a0, cst0);
        const float h1v = cellup(a1, cst1);
        const float h2v = cellup(a2, cst2);
        if (rok) {
            *(short*)(a1w + wof0) = f2bf(h0);
            *(short*)(a1w + wof1) = f2bf(h1v);
            *(short*)(a1w + wof2) = f2bf(h2v);
        }
        if (s > 0) {
            const float h4v = cellup(a4, cst4);
            if (rok) *(short*)(h2w + wof4) = f2bf(h4v);
        }
        if (wv == 0 || (s > 0 && wv <= 5)) {
            const float h3v = cellup(a3, cst3);
            char* d3 = (wv == 0) ? a1w : h2w;
            if (ok3 && rok) *(short*)(d3 + wof3) = f2bf(h3v);
        }
        __syncthreads();
    }

    // ==== peeled final superstep (s=256): L2 computes h2(255) -> hscr ====
    {
        char* a1r = a1b;      // s=256 even -> buf0
        char* h2r = h2bb;
        const bf16x8 bA0 = *(const bf16x8*)(a1r + 0 * 1024 + lane * 16);
        const bf16x8 bA1 = *(const bf16x8*)(a1r + 1 * 1024 + lane * 16);
        const bf16x8 bA2 = *(const bf16x8*)(a1r + 2 * 1024 + lane * 16);
        const bf16x8 bA3 = *(const bf16x8*)(a1r + 3 * 1024 + lane * 16);
        const bf16x8 bH0 = *(const bf16x8*)(h2r + 0 * 1024 + lane * 16);
        const bf16x8 bH1 = *(const bf16x8*)(h2r + 1 * 1024 + lane * 16);

        f32x4 a3 = MFMA(wfB[0], bA0, bv3);
        f32x4 a4 = MFMA(wfC[0], bA0, bv4);
        a3 = MFMA(wfB[1], bA1, a3);
        a4 = MFMA(wfC[1], bA1, a4);
        a3 = MFMA(wfB[2], bA2, a3);
        a4 = MFMA(wfC[2], bA2, a4);
        a3 = MFMA(wfB[3], bA3, a3);
        a4 = MFMA(wfC[3], bA3, a4);
        a3 = MFMA(wfB[4], bH0, a3);
        a4 = MFMA(wfC[4], bH0, a4);
        a3 = MFMA(wfB[5], bH1, a3);
        a4 = MFMA(wfC[5], bH1, a4);

        if (wv >= 1 && wv <= 5) {
            const float h3v = cellup(a3, cst3);
            if (ok3 && rok) hscr[hso3] = h3v;
        }
        {
            const float h4v = cellup(a4, cst4);
            if (rok) hscr[hso4] = h4v;
        }
        __syncthreads();
    }

    // ---- dense head ----
    if (tid < ROWS) {
        float acc = bd[0];
#pragma unroll 2
        for (int u = 0; u < H2; ++u) acc = fmaf(hscr[tid * 52 + u], Wd[u], acc);
        out[row0 + tid] = acc;
    }
}

extern "C" void kernel_launch(void* const* d_in, const int* in_sizes, int n_in,
                              void* d_out, int out_size, void* d_ws, size_t ws_size,
                              hipStream_t stream) {
    const float* x     = (const float*)d_in[0];
    const float* W_ih1 = (const float*)d_in[1];
    const float* W_hh1 = (const float*)d_in[2];
    const float* b_ih1 = (const float*)d_in[3];
    const float* b_hh1 = (const float*)d_in[4];
    const float* W_ih2 = (const float*)d_in[5];
    const float* W_hh2 = (const float*)d_in[6];
    const float* b_ih2 = (const float*)d_in[7];
    const float* b_hh2 = (const float*)d_in[8];
    const float* Wd    = (const float*)d_in[9];
    const float* bd    = (const float*)d_in[10];
    float* out = (float*)d_out;

    hipLaunchKernelGGL(lstm_ws6, dim3(NBLK), dim3(NT), 0, stream,
                       x, W_ih1, W_hh1, b_ih1, b_hh1,
                       W_ih2, W_hh2, b_ih2, b_hh2, Wd, bd, out);
}

// Round 12
// 393.538 us; speedup vs baseline: 4.9569x; 4.9569x over previous
//
#include <hip/hip_runtime.h>
#include <math.h>

#define TT 256
#define H1 100
#define H2 50
#define NT 1024
#define NBLK 256   // 4096 rows / 16 per block; 1 block per CU
#define ROWS 16

typedef __attribute__((ext_vector_type(8))) short bf16x8;
typedef __attribute__((ext_vector_type(4))) float f32x4;

// round-half-up bf16 (ties ~2^-16, sign-symmetric; 2 instrs vs 5 for full RNE)
__device__ __forceinline__ short f2bf(float f) {
    union { float f; unsigned u; } v; v.f = f;
    return (short)((v.u + 0x8000u) >> 16);
}

// fragment-linear byte offset: element (K,R) of a [chunk][64 lane][8 bf16] buf
__device__ __forceinline__ int off_frag(int K, int R) {
    return (K >> 5) * 1024 + ((K >> 3) & 3) * 256 + R * 16 + (K & 7) * 2;
}

#define MFMA(w, b, c) __builtin_amdgcn_mfma_f32_16x16x32_bf16(w, b, c, 0, 0, 0)

// shared-rcp cellup: 8 trans (5 exp + 3 rcp) instead of 10.
// sig(i)=1/(1+e^-i)=df*rcp(di*df), sig(f)=di*rcp(di*df);
// sig(o)=dg*rcp(do*dg), tanh(g)=1-2*do*rcp(do*dg).
// Overflow-safe: |gate preact| <~10 -> exp <= e^20 finite; c-tanh rcp separate.
__device__ __forceinline__ float cellup(const f32x4& a, float& cst) {
    const float ei = __expf(-a[0]);
    const float ef = __expf(-a[1]);
    const float eg = __expf(2.0f * a[2]);
    const float eo = __expf(-a[3]);
    const float di = 1.0f + ei, df = 1.0f + ef;
    const float dg = 1.0f + eg, dq = 1.0f + eo;
    const float rif = __builtin_amdgcn_rcpf(di * df);
    const float rog = __builtin_amdgcn_rcpf(dq * dg);
    const float is = df * rif, fs = di * rif;
    const float os = dg * rog;
    const float gt = 1.0f - 2.0f * (dq * rog);
    const float c = fs * cst + is * gt;
    cst = c;
    const float th = 1.0f - 2.0f * __builtin_amdgcn_rcpf(1.0f + __expf(2.0f * c));
    return os * th;
}

// ---- weight fragment loaders (round-4/7 proven numerics; run once) ----
// full-RNE conversion for weights (one-time cost)
__device__ __forceinline__ short f2bf_rne(float f) {
    union { float f; unsigned u; } v; v.f = f;
    unsigned r = v.u + 0x7FFFu + ((v.u >> 16) & 1u);
    return (short)(r >> 16);
}
__device__ __forceinline__ void load_w1(bf16x8* dst, int T, int r, int q,
                                        const float* W_hh1, const float* W_ih1) {
    const int jp = T * 16 + r, g = jp & 3, uu = jp >> 2;   // uu < 100
#pragma unroll
    for (int c = 0; c < 4; ++c) {
        bf16x8 w;
#pragma unroll
        for (int i = 0; i < 8; ++i) {
            const int k = c * 32 + q * 8 + i;
            float f = 0.f;
            if (k < H1) f = W_hh1[(g * H1 + uu) * H1 + k];
            else if (k < H1 + 8) f = W_ih1[(g * H1 + uu) * 8 + (k - H1)];
            w[i] = f2bf_rne(f);
        }
        dst[c] = w;
    }
}
// L2 weights: chunks 0-3 (h1 part) -> dstA, chunks 4-5 (h2 part) -> dstH
__device__ __forceinline__ void load_w2(bf16x8* dstA, bf16x8* dstH, int t2,
                                        int r, int q,
                                        const float* W_ih2, const float* W_hh2) {
    const int jp = t2 * 16 + r, g = jp & 3, uu = jp >> 2;
    const bool ok = uu < H2;
#pragma unroll
    for (int c = 0; c < 4; ++c) {
        bf16x8 w;
#pragma unroll
        for (int i = 0; i < 8; ++i) {
            const int k = c * 32 + q * 8 + i;
            float f = 0.f;
            if (ok && k < H1) f = W_ih2[(g * H2 + uu) * H1 + k];
            w[i] = f2bf_rne(f);
        }
        dstA[c] = w;
    }
#pragma unroll
    for (int c = 0; c < 2; ++c) {
        bf16x8 w;
#pragma unroll
        for (int i = 0; i < 8; ++i) {
            const int k2 = c * 32 + q * 8 + i;
            float f = 0.f;
            if (ok && k2 < H2) f = W_hh2[(g * H2 + uu) * H2 + k2];
            w[i] = f2bf_rne(f);
        }
        dstH[c] = w;
    }
}

__global__ __launch_bounds__(NT) void lstm_ws7(
    const float* __restrict__ x,
    const float* __restrict__ W_ih1, const float* __restrict__ W_hh1,
    const float* __restrict__ b_ih1, const float* __restrict__ b_hh1,
    const float* __restrict__ W_ih2, const float* __restrict__ W_hh2,
    const float* __restrict__ b_ih2, const float* __restrict__ b_hh2,
    const float* __restrict__ Wd, const float* __restrict__ bd,
    float* __restrict__ out)
{
    __shared__ __align__(16) short xb[TT * ROWS * 8];   // 64 KB bf16 x
    __shared__ __align__(16) short A1h[2 * 4 * 64 * 8]; // 8 KB
    __shared__ __align__(16) short h2b[2 * 2 * 64 * 8]; // 4 KB
    __shared__ float hscr[ROWS * 52];

    const int tid = threadIdx.x;
    const int lane = tid & 63;
    const int wv = tid >> 6;       // 16 waves
    const int r = lane & 15;
    const int q = lane >> 4;
    const int row0 = blockIdx.x * ROWS;

    char* const a1b = (char*)A1h;
    char* const h2bb = (char*)h2b;

    // ---- fill xb ----
    {
        const float* xg = x + (size_t)row0 * (TT * 8);
#pragma unroll
        for (int it = 0; it < 8; ++it) {
            const int f = (it * NT + tid) * 4;
            const float4 v = *(const float4*)(xg + f);
            const int rr = f >> 11, rem = f & 2047, t = rem >> 3, k = rem & 7;
            uint2 pk;
            pk.x = (unsigned short)f2bf(v.x) | ((unsigned)(unsigned short)f2bf(v.y) << 16);
            pk.y = (unsigned short)f2bf(v.z) | ((unsigned)(unsigned short)f2bf(v.w) << 16);
            *(uint2*)((char*)xb + t * 256 + rr * 16 + k * 2) = pk;
        }
    }
    for (int i = tid; i < 2 * 4 * 64 * 8; i += NT) A1h[i] = 0;
    for (int i = tid; i < 2 * 2 * 64 * 8; i += NT) h2b[i] = 0;
    if (tid < ROWS * 52) hscr[tid] = 0.f;

    // ---- slot composition (38 tiles over 16 waves, zero dead slots) ----
    // slot0: L1 tile wv (0..15)                  -> always
    // slot1: wv<=8 -> L1 tile 16+wv (16..24); wv>=9 -> L2 tile wv-9 (0..6)
    // slot2: wv<=5 -> L2 tile 7+wv (7..12); else none
    const bool s1isL1 = (wv <= 8);
    const bool hasS2 = (wv <= 5);

    bf16x8 wf0[4], wf1[4], wf2[4], wH[2];
    const bf16x8 zf = (bf16x8){0, 0, 0, 0, 0, 0, 0, 0};
#pragma unroll
    for (int c = 0; c < 4; ++c) wf2[c] = zf;
    wH[0] = zf; wH[1] = zf;

    f32x4 bv0, bv1, bv2 = {0.f, 0.f, 0.f, 0.f};
    int wof0, wof1, wof2 = 0;
    int hso1 = 0, hso2 = 0;
    bool ok2 = false;

    load_w1(wf0, wv, r, q, W_hh1, W_ih1);
    {
        const int u0 = wv * 4 + q;   // 0..63
#pragma unroll
        for (int g = 0; g < 4; ++g) bv0[g] = b_ih1[g * H1 + u0] + b_hh1[g * H1 + u0];
        wof0 = off_frag(u0, r);
    }
    if (s1isL1) {
        load_w1(wf1, 16 + wv, r, q, W_hh1, W_ih1);
        const int u1 = (16 + wv) * 4 + q;   // 64..99
#pragma unroll
        for (int g = 0; g < 4; ++g) bv1[g] = b_ih1[g * H1 + u1] + b_hh1[g * H1 + u1];
        wof1 = off_frag(u1, r);
    } else {
        load_w2(wf1, wH, wv - 9, r, q, W_ih2, W_hh2);
        const int u21 = (wv - 9) * 4 + q;   // 0..27, always < 50
#pragma unroll
        for (int g = 0; g < 4; ++g) bv1[g] = b_ih2[g * H2 + u21] + b_hh2[g * H2 + u21];
        wof1 = off_frag(u21, r);
        hso1 = r * 52 + u21;
    }
    if (hasS2) {
        load_w2(wf2, wH, 7 + wv, r, q, W_ih2, W_hh2);
        const int u22 = (7 + wv) * 4 + q;   // 28..51
        ok2 = (u22 < H2);
#pragma unroll
        for (int g = 0; g < 4; ++g)
            bv2[g] = ok2 ? (b_ih2[g * H2 + u22] + b_hh2[g * H2 + u22]) : 0.f;
        wof2 = off_frag(u22 & 63, r);
        hso2 = r * 52 + u22;
    }

    float cst0 = 0.f, cst1 = 0.f, cst2 = 0.f;

    const bool wstage = ((tid >> 4) == 24);   // wave 6 (lightest), lanes 0..15
    const int st = tid & 15;

    __syncthreads();
    // stage x(0) into buf0 chunk 3
    if (tid < ROWS) {
        bf16x8 v = *(const bf16x8*)((const char*)xb + tid * 16);
        uint2 lo = ((const uint2*)&v)[0], hi = ((const uint2*)&v)[1];
        char* dst = a1b + 3 * 1024 + tid * 16;
        *(uint2*)(dst + 8) = lo;
        *(uint2*)(dst + 256) = hi;
    }
    __syncthreads();

    // ==== main loop: superstep s computes h1(s) and (s>0) h2(s-1) ====
    for (int s = 0; s < TT; ++s) {
        const int cur = s & 1;
        char* a1r = a1b + (cur << 12);
        char* h2r = h2bb + (cur << 11);
        char* a1w = a1b + ((cur ^ 1) << 12);
        char* h2w = h2bb + ((cur ^ 1) << 11);

        const bf16x8 bA0 = *(const bf16x8*)(a1r + 0 * 1024 + lane * 16);
        const bf16x8 bA1 = *(const bf16x8*)(a1r + 1 * 1024 + lane * 16);
        const bf16x8 bA2 = *(const bf16x8*)(a1r + 2 * 1024 + lane * 16);
        const bf16x8 bA3 = *(const bf16x8*)(a1r + 3 * 1024 + lane * 16);
        // unconditional: valid LDS for every wave; zeros when unused
        const bf16x8 bH0 = *(const bf16x8*)(h2r + 0 * 1024 + lane * 16);
        const bf16x8 bH1 = *(const bf16x8*)(h2r + 1 * 1024 + lane * 16);

        if (wstage && s + 1 < TT) {
            bf16x8 v = *(const bf16x8*)((const char*)xb + (s + 1) * 256 + st * 16);
            uint2 lo = ((const uint2*)&v)[0], hi = ((const uint2*)&v)[1];
            char* dst = a1w + 3 * 1024 + st * 16;
            *(uint2*)(dst + 8) = lo;
            *(uint2*)(dst + 256) = hi;
        }

        // ---- MFMAs: slots 0/1 two-way interleaved; slot2 after ----
        f32x4 a0 = MFMA(wf0[0], bA0, bv0);
        f32x4 a1 = MFMA(wf1[0], bA0, bv1);
        a0 = MFMA(wf0[1], bA1, a0);
        a1 = MFMA(wf1[1], bA1, a1);
        a0 = MFMA(wf0[2], bA2, a0);
        a1 = MFMA(wf1[2], bA2, a1);
        a0 = MFMA(wf0[3], bA3, a0);
        a1 = MFMA(wf1[3], bA3, a1);
        if (!s1isL1) {
            a1 = MFMA(wH[0], bH0, a1);
            a1 = MFMA(wH[1], bH1, a1);
        }
        f32x4 a2 = bv2;
        if (hasS2) {
            a2 = MFMA(wf2[0], bA0, a2);
            a2 = MFMA(wf2[1], bA1, a2);
            a2 = MFMA(wf2[2], bA2, a2);
            a2 = MFMA(wf2[3], bA3, a2);
            a2 = MFMA(wH[0], bH0, a2);
            a2 = MFMA(wH[1], bH1, a2);
        }

        // ---- nonlinearities + state writes ----
        const float h0 = cellup(a0, cst0);
        *(short*)(a1w + wof0) = f2bf(h0);

        if (s1isL1) {
            const float h1v = cellup(a1, cst1);
            *(short*)(a1w + wof1) = f2bf(h1v);
        } else if (s > 0) {
            const float h1v = cellup(a1, cst1);
            *(short*)(h2w + wof1) = f2bf(h1v);
        }
        if (hasS2 && s > 0) {
            const float h2v = cellup(a2, cst2);
            if (ok2) *(short*)(h2w + wof2) = f2bf(h2v);
        }
        __syncthreads();
    }

    // ==== peeled final superstep (s=256): L2 computes h2(255) -> hscr ====
    {
        char* a1r = a1b;      // s=256 even -> buf0
        char* h2r = h2bb;
        if (!s1isL1 || hasS2) {
            const bf16x8 bA0 = *(const bf16x8*)(a1r + 0 * 1024 + lane * 16);
            const bf16x8 bA1 = *(const bf16x8*)(a1r + 1 * 1024 + lane * 16);
            const bf16x8 bA2 = *(const bf16x8*)(a1r + 2 * 1024 + lane * 16);
            const bf16x8 bA3 = *(const bf16x8*)(a1r + 3 * 1024 + lane * 16);
            const bf16x8 bH0 = *(const bf16x8*)(h2r + 0 * 1024 + lane * 16);
            const bf16x8 bH1 = *(const bf16x8*)(h2r + 1 * 1024 + lane * 16);

            if (!s1isL1) {
                f32x4 a1 = MFMA(wf1[0], bA0, bv1);
                a1 = MFMA(wf1[1], bA1, a1);
                a1 = MFMA(wf1[2], bA2, a1);
                a1 = MFMA(wf1[3], bA3, a1);
                a1 = MFMA(wH[0], bH0, a1);
                a1 = MFMA(wH[1], bH1, a1);
                const float h1v = cellup(a1, cst1);
                hscr[hso1] = h1v;
            }
            if (hasS2) {
                f32x4 a2 = bv2;
                a2 = MFMA(wf2[0], bA0, a2);
                a2 = MFMA(wf2[1], bA1, a2);
                a2 = MFMA(wf2[2], bA2, a2);
                a2 = MFMA(wf2[3], bA3, a2);
                a2 = MFMA(wH[0], bH0, a2);
                a2 = MFMA(wH[1], bH1, a2);
                const float h2v = cellup(a2, cst2);
                if (ok2) hscr[hso2] = h2v;
            }
        }
        __syncthreads();
    }

    // ---- dense head ----
    if (tid < ROWS) {
        float acc = bd[0];
#pragma unroll 2
        for (int u = 0; u < H2; ++u) acc = fmaf(hscr[tid * 52 + u], Wd[u], acc);
        out[row0 + tid] = acc;
    }
}

extern "C" void kernel_launch(void* const* d_in, const int* in_sizes, int n_in,
                              void* d_out, int out_size, void* d_ws, size_t ws_size,
                              hipStream_t stream) {
    const float* x     = (const float*)d_in[0];
    const float* W_ih1 = (const float*)d_in[1];
    const float* W_hh1 = (const float*)d_in[2];
    const float* b_ih1 = (const float*)d_in[3];
    const float* b_hh1 = (const float*)d_in[4];
    const float* W_ih2 = (const float*)d_in[5];
    const float* W_hh2 = (const float*)d_in[6];
    const float* b_ih2 = (const float*)d_in[7];
    const float* b_hh2 = (const float*)d_in[8];
    const float* Wd    = (const float*)d_in[9];
    const float* bd    = (const float*)d_in[10];
    float* out = (float*)d_out;

    hipLaunchKernelGGL(lstm_ws7, dim3(NBLK), dim3(NT), 0, stream,
                       x, W_ih1, W_hh1, b_ih1, b_hh1,
                       W_ih2, W_hh2, b_ih2, b_hh2, Wd, bd, out);
}